// Round 9
// baseline (231.025 us; speedup 1.0000x reference)
//
#include <hip/hip_runtime.h>
#include <hip/hip_bf16.h>
#include <cstdint>
#include <cstddef>

// SheafConvLayer via linearity: u = diag*x + A_norm x ; cb = diag + rowsum
// out = x - 0.5*(u @ W^T + cb (x) b).   N=50000, D=512, E=200000.
// Round 9: fuse gather+GEMM (kill the 102.4 MB ub round-trip).

#define DD 512
#define STEPSZ 0.5f
#define SLOTS 32

typedef __bf16 bf16;
typedef __bf16 bf16x8 __attribute__((ext_vector_type(8)));
typedef __bf16 bf16x4 __attribute__((ext_vector_type(4)));
typedef float f32x4 __attribute__((ext_vector_type(4)));

#define GLOAD16(g, l)                                                     \
  __builtin_amdgcn_global_load_lds(                                       \
      (const __attribute__((address_space(1))) void*)(g),                 \
      (__attribute__((address_space(3))) void*)(l), 16, 0, 0)

// ------- stage 1: fused W->bf16 + zblock zero (blocks 0..255) -------------
//         + x->bf16 / s,t (remaining blocks)
__global__ __launch_bounds__(256) void k_prep(
    const float* __restrict__ x, const float* __restrict__ wsheaf,
    const float* __restrict__ wlin, bf16* __restrict__ xbf,
    bf16* __restrict__ wbf, float* __restrict__ s, float* __restrict__ t,
    float* __restrict__ dmaps, int* __restrict__ fill, int n) {
  if (blockIdx.x < 256) {  // 256 blocks * 256 thr * 4 = 262144 = DD*DD
    int i = (blockIdx.x * 256 + threadIdx.x) * 4;
    float4 v = *(const float4*)(wlin + i);
    bf16x4 p;
    p[0] = (bf16)v.x; p[1] = (bf16)v.y; p[2] = (bf16)v.z; p[3] = (bf16)v.w;
    *(bf16x4*)(wbf + i) = p;
    int zi = blockIdx.x * 256 + threadIdx.x;  // 0..65535 >= n
    if (zi < n) { dmaps[zi] = 0.0f; fill[zi] = 0; }
    return;
  }
  int lane = threadIdx.x & 63;
  int row = ((blockIdx.x - 256) << 2) + (threadIdx.x >> 6);
  if (row >= n) return;
  const float* xr = x + (size_t)row * DD + lane * 8;
  float4 a = *(const float4*)xr;
  float4 b = *(const float4*)(xr + 4);
  bf16x8 p;
  p[0] = (bf16)a.x; p[1] = (bf16)a.y; p[2] = (bf16)a.z; p[3] = (bf16)a.w;
  p[4] = (bf16)b.x; p[5] = (bf16)b.y; p[6] = (bf16)b.z; p[7] = (bf16)b.w;
  *(bf16x8*)(xbf + (size_t)row * DD + lane * 8) = p;
  const float* w1 = wsheaf + lane * 8;
  const float* w2 = wsheaf + DD + lane * 8;
  float4 wa = *(const float4*)w1, wb = *(const float4*)(w1 + 4);
  float4 wc = *(const float4*)w2, wd = *(const float4*)(w2 + 4);
  float sv = a.x * wa.x + a.y * wa.y + a.z * wa.z + a.w * wa.w +
             b.x * wb.x + b.y * wb.y + b.z * wb.z + b.w * wb.w;
  float tv = a.x * wc.x + a.y * wc.y + a.z * wc.z + a.w * wc.w +
             b.x * wd.x + b.y * wd.y + b.z * wd.z + b.w * wd.w;
  #pragma unroll
  for (int o = 32; o > 0; o >>= 1) {
    sv += __shfl_xor(sv, o);
    tv += __shfl_xor(tv, o);
  }
  if (lane == 0) { s[row] = sv; t[row] = tv; }
}

// ------- stage 2: edges: diag atomics + unnormalized slot fill ------------
__global__ __launch_bounds__(256) void k_fill(
    const int* __restrict__ ei, const float* __restrict__ s,
    const float* __restrict__ t, float* __restrict__ dmaps,
    int* __restrict__ fill, int* __restrict__ ccol, float* __restrict__ cval,
    int E) {
  int e = blockIdx.x * 256 + threadIdx.x;
  if (e >= E) return;
  int r = ei[e], c = ei[E + e];
  float sr = s[r], tc = t[c], sc = s[c], tr = t[r];
  float me = tanhf(sr + tc);
  float mr = tanhf(sc + tr);
  atomicAdd(dmaps + r, me * me);
  int p = atomicAdd(fill + r, 1);
  if (p < SLOTS) {
    ccol[(size_t)r * SLOTS + p] = c;
    cval[(size_t)r * SLOTS + p] = -me * mr;  // normalized in k_mega
  }
}

// ------- stage 3: FUSED gather + GEMM + epilogue --------------------------
// Block = 64 rows x all 512 cols. Phase 1: gather u rows into a 64KB LDS
// A-tile (8-slot XOR bank swizzle; ds_write side conflict-free, MFMA read
// 2-way = free). cb[64] parked in the B region, shfl-broadcast to registers
// before B staging overwrites it (double barrier). Phase 2: flat 64-step
// (nc,t) pipelined loop, B tiles [128][32] double-buffered via
// global_load_lds (pre-swizzled source, slot = lhi ^ ((col>>1)&3) -> 2-way).
// Epilogue per nc: out = xb - 0.5*(acc + cb*b), 64B-dense fp32 stores.
// LDS exactly 80KB -> 2 blocks/CU.
__global__ __launch_bounds__(256, 2) void k_mega(
    const bf16* __restrict__ xb, const bf16* __restrict__ wbf,
    const float* __restrict__ bias, const float* __restrict__ dmaps,
    const int* __restrict__ fill, const int* __restrict__ ccol,
    const float* __restrict__ cval, float* __restrict__ out, int n) {
  __shared__ __align__(16) char smem[81920];
  bf16* At = (bf16*)smem;               // [64][512] chunk-swizzled
  bf16* Bt = (bf16*)(smem + 65536);     // 2 x [128][32]
  float* cbl = (float*)(smem + 65536);  // transient (gather phase only)
  int tid = threadIdx.x, w = tid >> 6, lane = tid & 63;
  int lhi = lane >> 4;
  int row0 = blockIdx.x * 64;
  unsigned nm1 = (unsigned)(n - 1);
  int c0 = lane * 8;

  // ---- phase 1: gather 16 rows per wave into A-tile ----
  for (int j = 0; j < 16; ++j) {
    int row = w * 16 + j;
    unsigned gr = min((unsigned)(row0 + row), nm1);
    float dm = dmaps[gr];
    float inv_r = rsqrtf(dm + 1.0f);
    float dg = dm / (dm + 1.0f);
    bf16x8 xv = *(const bf16x8*)(xb + (size_t)gr * DD + c0);
    float acc[8];
    #pragma unroll
    for (int k = 0; k < 8; ++k) acc[k] = dg * (float)xv[k];
    int cnt = fill[gr];
    if (cnt > SLOTS) cnt = SLOTS;
    const int* cc = ccol + (size_t)gr * SLOTS;
    const float* cv = cval + (size_t)gr * SLOTS;
    float cbs = 0.0f;
    for (int i = 0; i < cnt; i += 4) {
      int4 c4 = *(const int4*)(cc + i);
      float4 v4 = *(const float4*)(cv + i);
      int rem = cnt - i;
      unsigned ca = min((unsigned)c4.x, nm1);
      unsigned cb2 = min((unsigned)c4.y, nm1);
      unsigned cg = min((unsigned)c4.z, nm1);
      unsigned cd = min((unsigned)c4.w, nm1);
      bf16x8 na = *(const bf16x8*)(xb + (size_t)ca * DD + c0);
      bf16x8 nb = *(const bf16x8*)(xb + (size_t)cb2 * DD + c0);
      bf16x8 ng = *(const bf16x8*)(xb + (size_t)cg * DD + c0);
      bf16x8 nd = *(const bf16x8*)(xb + (size_t)cd * DD + c0);
      float va = rem > 0 ? v4.x * inv_r * rsqrtf(dmaps[ca] + 1.0f) : 0.0f;
      float vb = rem > 1 ? v4.y * inv_r * rsqrtf(dmaps[cb2] + 1.0f) : 0.0f;
      float vg = rem > 2 ? v4.z * inv_r * rsqrtf(dmaps[cg] + 1.0f) : 0.0f;
      float vd = rem > 3 ? v4.w * inv_r * rsqrtf(dmaps[cd] + 1.0f) : 0.0f;
      cbs += va + vb + vg + vd;
      #pragma unroll
      for (int k = 0; k < 8; ++k)
        acc[k] += va * (float)na[k] + vb * (float)nb[k] + vg * (float)ng[k] +
                  vd * (float)nd[k];
    }
    #pragma unroll
    for (int o = 32; o > 0; o >>= 1) cbs += __shfl_xor(cbs, o);
    bf16x8 o8;
    #pragma unroll
    for (int k = 0; k < 8; ++k) o8[k] = (bf16)acc[k];
    // logical k-chunk = lane, physical = lane ^ (row&7)  (conflict-free wr)
    *(bf16x8*)(At + row * DD + ((lane ^ (row & 7)) << 3)) = o8;
    if (lane == 0) cbl[row] = dg + cbs;
  }
  __syncthreads();
  float cbreg = cbl[lane];  // each lane holds cb[lane] (rows 0..63)
  __syncthreads();          // cb reads done before B staging overwrites

  // ---- phase 2: GEMM, flat pipelined (nc,t) loop ----
  int rl = lane >> 2;
  int p0[2];
  bf16* dst0[2];
  #pragma unroll
  for (int c = 0; c < 2; ++c) {
    int rbase = c * 64 + w * 16 + rl;  // W row (= output col) within 128
    int kc = (lane & 3) ^ ((rbase >> 1) & 3);  // pre-swizzled source chunk
    p0[c] = rbase * DD + kc * 8;
    dst0[c] = Bt + (c * 64 + w * 16) * 32;  // wave-uniform LDS base
  }
  f32x4 acc[4][2] = {};
  {  // prologue: stage ft=0
    #pragma unroll
    for (int c = 0; c < 2; ++c) GLOAD16(wbf + p0[c], dst0[c]);
  }
  __syncthreads();
  for (int ft = 0; ft < 64; ++ft) {
    if (ft + 1 < 64) {
      int off = ((ft + 1) >> 4) * 65536 + ((ft + 1) & 15) * 32;
      int bsel = ((ft + 1) & 1) * 4096;
      #pragma unroll
      for (int c = 0; c < 2; ++c)
        GLOAD16(wbf + p0[c] + off, dst0[c] + bsel);
    }
    int t = ft & 15, bsel = (ft & 1) * 4096;
    bf16x8 af[4], bfr[2];
    #pragma unroll
    for (int m = 0; m < 4; ++m) {
      int r = (lane & 15) + m * 16;
      int slot = (t * 4 + lhi) ^ (lane & 7);
      af[m] = *(const bf16x8*)(At + r * DD + slot * 8);
    }
    #pragma unroll
    for (int nn = 0; nn < 2; ++nn) {
      int lc = w * 32 + nn * 16 + (lane & 15);
      int slot = lhi ^ ((lc >> 1) & 3);
      bfr[nn] = *(const bf16x8*)(Bt + bsel + lc * 32 + slot * 8);
    }
    #pragma unroll
    for (int m = 0; m < 4; ++m)
      #pragma unroll
      for (int nn = 0; nn < 2; ++nn)
        acc[m][nn] = __builtin_amdgcn_mfma_f32_16x16x32_bf16(
            af[m], bfr[nn], acc[m][nn], 0, 0, 0);
    __syncthreads();  // drains next-tile loads AFTER compute (pipelined)
    if (t == 15) {
      // epilogue for this nc: out = xb - 0.5*(acc + cb*b)
      int nc = ft >> 4;
      int gc0 = nc * 128 + w * 32;
      int cl = lane & 15;
      float bv0 = bias[gc0 + cl];
      float bv1 = bias[gc0 + 16 + cl];
      #pragma unroll
      for (int m = 0; m < 4; ++m)
        #pragma unroll
        for (int rr = 0; rr < 4; ++rr) {
          int rloc = m * 16 + lhi * 4 + rr;
          float cbv = __shfl(cbreg, rloc);
          int growg = row0 + rloc;
          if (growg < n) {
            size_t base = (size_t)growg * DD + gc0;
            float x0 = (float)xb[base + cl];
            float x1 = (float)xb[base + 16 + cl];
            out[base + cl] = x0 - STEPSZ * (acc[m][0][rr] + cbv * bv0);
            out[base + 16 + cl] = x1 - STEPSZ * (acc[m][1][rr] + cbv * bv1);
          }
        }
      #pragma unroll
      for (int m = 0; m < 4; ++m)
        #pragma unroll
        for (int nn = 0; nn < 2; ++nn)
          acc[m][nn] = (f32x4){0.0f, 0.0f, 0.0f, 0.0f};
    }
  }
}

extern "C" void kernel_launch(void* const* d_in, const int* in_sizes, int n_in,
                              void* d_out, int out_size, void* d_ws,
                              size_t ws_size, hipStream_t stream) {
  const float* x = (const float*)d_in[0];
  const float* W = (const float*)d_in[1];
  const float* b = (const float*)d_in[2];
  const float* wsheaf = (const float*)d_in[3];
  const int* ei = (const int*)d_in[4];
  const int* right = (const int*)d_in[5];
  (void)right;
  int N = in_sizes[0] / DD;  // 50000
  int E = in_sizes[5];       // 200000

  char* ws = (char*)d_ws;
  size_t p = 0;
  auto alloc = [&](size_t bytes) -> char* {
    char* r = ws + p;
    p += (bytes + 255) & ~(size_t)255;
    return r;
  };
  // ~65.3 MB total (same budget that fit in rounds 1-8)
  bf16* xbf = (bf16*)alloc((size_t)N * DD * 2);        // 51.2 MB
  float* cval = (float*)alloc((size_t)N * SLOTS * 4);  // 6.4 MB
  int* ccol = (int*)alloc((size_t)N * SLOTS * 4);      // 6.4 MB
  float* s = (float*)alloc((size_t)N * 4);
  float* t = (float*)alloc((size_t)N * 4);
  bf16* wbf = (bf16*)alloc((size_t)DD * DD * 2);
  char* zblock = alloc((size_t)N * 8);
  float* diag_maps = (float*)zblock;
  int* fill = (int*)(zblock + (size_t)N * 4);

  k_prep<<<256 + (N + 3) / 4, 256, 0, stream>>>(x, wsheaf, W, xbf, wbf, s, t,
                                                diag_maps, fill, N);
  k_fill<<<(E + 255) / 256, 256, 0, stream>>>(ei, s, t, diag_maps, fill, ccol,
                                              cval, E);
  k_mega<<<(N + 63) / 64, 256, 0, stream>>>(xbf, wbf, b, diag_maps, fill,
                                            ccol, cval, (float*)d_out, N);
}

// Round 11
// 156.428 us; speedup vs baseline: 1.4769x; 1.4769x over previous
//
#include <hip/hip_runtime.h>
#include <hip/hip_bf16.h>
#include <cstdint>
#include <cstddef>

// SheafConvLayer via linearity: u = diag*x + A_norm x ; cb = diag + rowsum
// out = x - 0.5*(u @ W^T + cb (x) b).   N=50000, D=512, E=200000.
// Round 11: round-10 counted-vmcnt schedule + FULL sched_barrier fencing
// (rule 18: raw s_barrier is not a code-motion fence in hipcc; round-10's
// unfenced version raced -> tripwire).

#define DD 512
#define STEPSZ 0.5f
#define SLOTS 32

typedef __bf16 bf16;
typedef __bf16 bf16x8 __attribute__((ext_vector_type(8)));
typedef __bf16 bf16x4 __attribute__((ext_vector_type(4)));
typedef float f32x4 __attribute__((ext_vector_type(4)));

#define GLOAD16(g, l)                                                     \
  __builtin_amdgcn_global_load_lds(                                       \
      (const __attribute__((address_space(1))) void*)(g),                 \
      (__attribute__((address_space(3))) void*)(l), 16, 0, 0)
#define SB0() __builtin_amdgcn_sched_barrier(0)

// ------- stage 1: fused W->bf16 + zblock zero (blocks 0..255) -------------
//         + x->bf16 / s,t (remaining blocks)
__global__ __launch_bounds__(256) void k_prep(
    const float* __restrict__ x, const float* __restrict__ wsheaf,
    const float* __restrict__ wlin, bf16* __restrict__ xbf,
    bf16* __restrict__ wbf, float* __restrict__ s, float* __restrict__ t,
    float* __restrict__ dmaps, int* __restrict__ fill, int n) {
  if (blockIdx.x < 256) {  // 256 blocks * 256 thr * 4 = 262144 = DD*DD
    int i = (blockIdx.x * 256 + threadIdx.x) * 4;
    float4 v = *(const float4*)(wlin + i);
    bf16x4 p;
    p[0] = (bf16)v.x; p[1] = (bf16)v.y; p[2] = (bf16)v.z; p[3] = (bf16)v.w;
    *(bf16x4*)(wbf + i) = p;
    int zi = blockIdx.x * 256 + threadIdx.x;  // 0..65535 >= n
    if (zi < n) { dmaps[zi] = 0.0f; fill[zi] = 0; }
    return;
  }
  int lane = threadIdx.x & 63;
  int row = ((blockIdx.x - 256) << 2) + (threadIdx.x >> 6);
  if (row >= n) return;
  const float* xr = x + (size_t)row * DD + lane * 8;
  float4 a = *(const float4*)xr;
  float4 b = *(const float4*)(xr + 4);
  bf16x8 p;
  p[0] = (bf16)a.x; p[1] = (bf16)a.y; p[2] = (bf16)a.z; p[3] = (bf16)a.w;
  p[4] = (bf16)b.x; p[5] = (bf16)b.y; p[6] = (bf16)b.z; p[7] = (bf16)b.w;
  *(bf16x8*)(xbf + (size_t)row * DD + lane * 8) = p;
  const float* w1 = wsheaf + lane * 8;
  const float* w2 = wsheaf + DD + lane * 8;
  float4 wa = *(const float4*)w1, wb = *(const float4*)(w1 + 4);
  float4 wc = *(const float4*)w2, wd = *(const float4*)(w2 + 4);
  float sv = a.x * wa.x + a.y * wa.y + a.z * wa.z + a.w * wa.w +
             b.x * wb.x + b.y * wb.y + b.z * wb.z + b.w * wb.w;
  float tv = a.x * wc.x + a.y * wc.y + a.z * wc.z + a.w * wc.w +
             b.x * wd.x + b.y * wd.y + b.z * wd.z + b.w * wd.w;
  #pragma unroll
  for (int o = 32; o > 0; o >>= 1) {
    sv += __shfl_xor(sv, o);
    tv += __shfl_xor(tv, o);
  }
  if (lane == 0) { s[row] = sv; t[row] = tv; }
}

// ------- stage 2: edges: diag atomics + unnormalized slot fill ------------
__global__ __launch_bounds__(256) void k_fill(
    const int* __restrict__ ei, const float* __restrict__ s,
    const float* __restrict__ t, float* __restrict__ dmaps,
    int* __restrict__ fill, int* __restrict__ ccol, float* __restrict__ cval,
    int E) {
  int e = blockIdx.x * 256 + threadIdx.x;
  if (e >= E) return;
  int r = ei[e], c = ei[E + e];
  float sr = s[r], tc = t[c], sc = s[c], tr = t[r];
  float me = tanhf(sr + tc);
  float mr = tanhf(sc + tr);
  atomicAdd(dmaps + r, me * me);
  int p = atomicAdd(fill + r, 1);
  if (p < SLOTS) {
    ccol[(size_t)r * SLOTS + p] = c;
    cval[(size_t)r * SLOTS + p] = -me * mr;  // normalized in k_gather
  }
}

// ------- stage 3: u = diag*xb + A_norm xb ; cb = diag + rowsum ------------
__global__ __launch_bounds__(256) void k_gather(
    const bf16* __restrict__ xb, const float* __restrict__ dmaps,
    const int* __restrict__ fill, const int* __restrict__ ccol,
    const float* __restrict__ cval, bf16* __restrict__ u,
    float* __restrict__ cb, int n) {
  int lane = threadIdx.x & 63;
  int row = (blockIdx.x << 2) + (threadIdx.x >> 6);
  if (row >= n) return;
  int c0 = lane * 8;
  float dm = dmaps[row];
  float inv_r = rsqrtf(dm + 1.0f);
  float dg = dm / (dm + 1.0f);
  bf16x8 xv = *(const bf16x8*)(xb + (size_t)row * DD + c0);
  float acc[8];
  #pragma unroll
  for (int j = 0; j < 8; ++j) acc[j] = dg * (float)xv[j];
  int cnt = fill[row];
  if (cnt > SLOTS) cnt = SLOTS;
  const int* cc = ccol + (size_t)row * SLOTS;
  const float* cv = cval + (size_t)row * SLOTS;
  unsigned nm1 = (unsigned)(n - 1);
  float cbs = 0.0f;
  for (int i = 0; i < cnt; i += 4) {
    int4 c4 = *(const int4*)(cc + i);
    float4 v4 = *(const float4*)(cv + i);
    int rem = cnt - i;
    unsigned ca = min((unsigned)c4.x, nm1);
    unsigned cbi = min((unsigned)c4.y, nm1);
    unsigned cg = min((unsigned)c4.z, nm1);
    unsigned cd = min((unsigned)c4.w, nm1);
    bf16x8 na = *(const bf16x8*)(xb + (size_t)ca * DD + c0);
    bf16x8 nb = *(const bf16x8*)(xb + (size_t)cbi * DD + c0);
    bf16x8 ng = *(const bf16x8*)(xb + (size_t)cg * DD + c0);
    bf16x8 nd = *(const bf16x8*)(xb + (size_t)cd * DD + c0);
    float va = rem > 0 ? v4.x * inv_r * rsqrtf(dmaps[ca] + 1.0f) : 0.0f;
    float vb = rem > 1 ? v4.y * inv_r * rsqrtf(dmaps[cbi] + 1.0f) : 0.0f;
    float vg = rem > 2 ? v4.z * inv_r * rsqrtf(dmaps[cg] + 1.0f) : 0.0f;
    float vd = rem > 3 ? v4.w * inv_r * rsqrtf(dmaps[cd] + 1.0f) : 0.0f;
    cbs += va + vb + vg + vd;
    #pragma unroll
    for (int j = 0; j < 8; ++j)
      acc[j] += va * (float)na[j] + vb * (float)nb[j] + vg * (float)ng[j] +
                vd * (float)nd[j];
  }
  bf16x8 o;
  #pragma unroll
  for (int j = 0; j < 8; ++j) o[j] = (bf16)acc[j];
  *(bf16x8*)(u + (size_t)row * DD + c0) = o;
  if (lane == 0) cb[row] = dg + cbs;
}

// ------- stage 4: GEMM out = x - 0.5*(u @ W^T + cb*b) ---------------------
// 128x128 tile, BK=32, 4 waves (2x2), wave 64x64 = 4x4 frags of 16x16x32.
// Swizzle key (row>>1)&3 (orthogonal to bank-parity bit). Counted vmcnt:
// GLOAD(t+1); vmcnt(4) [own batch t retired]; SB0; s_barrier; SB0;
// ds_read+MFMA; lgkmcnt(0); SB0; s_barrier; SB0.
// Every raw s_barrier is fenced on BOTH sides (rule 18: hipcc moves ops
// across raw barriers; unfenced round-10 version raced).
__global__ __launch_bounds__(256, 4) void k_gemm(
    const bf16* __restrict__ ub, const bf16* __restrict__ wbf,
    const float* __restrict__ bias, const float* __restrict__ x,
    const bf16* __restrict__ xb, const float* __restrict__ cb,
    float* __restrict__ out, int M, int nwg, int use_bf) {
  __shared__ __align__(16) char smem[36864];
  bf16* lds = (bf16*)smem;
  // elem offsets: A0=0, B0=4096, A1=8192, B1=12288 (each 128x32)
  int orig = blockIdx.x;
  int q = nwg >> 3, r = nwg & 7;
  int xcd = orig & 7;
  int wgid = (xcd < r ? xcd * (q + 1) : r * (q + 1) + (xcd - r) * q) +
             (orig >> 3);
  int bm = wgid >> 2, bn = wgid & 3;
  int tid = threadIdx.x, w = tid >> 6, lane = tid & 63;
  int wr = w >> 1, wc = w & 1;
  int lhi = lane >> 4;

  // staging: lane covers row_local = lane>>2, phys slot = lane&3 (linear
  // dest). Logical chunk at [row][phys] = phys ^ ((row>>1)&3).
  int row_local = lane >> 2;
  int kc = (lane & 3) ^ ((lane >> 3) & 3);  // (row_local>>1)&3 = (lane>>3)&3
  const bf16* gA[2];
  const bf16* gB[2];
  bf16* lA[2];
  bf16* lB[2];
  #pragma unroll
  for (int c = 0; c < 2; ++c) {
    int rloc = c * 64 + w * 16 + row_local;
    int ga = bm * 128 + rloc;
    if (ga > M - 1) ga = M - 1;
    gA[c] = ub + (size_t)ga * DD + kc * 8;
    gB[c] = wbf + (size_t)(bn * 128 + rloc) * DD + kc * 8;
    lA[c] = lds + (c * 64 + w * 16) * 32;         // wave-uniform base
    lB[c] = lds + 4096 + (c * 64 + w * 16) * 32;  // +lane*16B by HW
  }

  f32x4 acc[4][4] = {};
  int arow = (wr * 64 + (lane & 15)) * 32;
  int brow = (wc * 64 + (lane & 15)) * 32;
  int sl = (lhi ^ ((lane >> 1) & 3)) * 8;  // conflict-free read slot (elems)

  // prologue: stage tile 0 into buf0 (no drain - loop's vmcnt covers it)
  #pragma unroll
  for (int c = 0; c < 2; ++c) {
    GLOAD16(gA[c], lA[c]);
    GLOAD16(gB[c], lB[c]);
  }

  #pragma unroll
  for (int t = 0; t < 16; ++t) {
    int cbuf = (t & 1) * 8192;
    if (t + 1 < 16) {
      int nbuf = ((t + 1) & 1) * 8192;
      int k0 = (t + 1) * 32;
      #pragma unroll
      for (int c = 0; c < 2; ++c) {
        GLOAD16(gA[c] + k0, lA[c] + nbuf);
        GLOAD16(gB[c] + k0, lB[c] + nbuf);
      }
      asm volatile("s_waitcnt vmcnt(4)" ::: "memory");  // batch t retired
    } else {
      asm volatile("s_waitcnt vmcnt(0)" ::: "memory");  // final batch
    }
    SB0();
    __builtin_amdgcn_s_barrier();  // collective: everyone's batch t landed
    SB0();
    const bf16* base = lds + cbuf;
    bf16x8 af[4], bfr[4];
    #pragma unroll
    for (int m = 0; m < 4; ++m)
      af[m] = *(const bf16x8*)(base + arow + m * 512 + sl);
    #pragma unroll
    for (int nn = 0; nn < 4; ++nn)
      bfr[nn] = *(const bf16x8*)(base + 4096 + brow + nn * 512 + sl);
    #pragma unroll
    for (int m = 0; m < 4; ++m)
      #pragma unroll
      for (int nn = 0; nn < 4; ++nn)
        acc[m][nn] = __builtin_amdgcn_mfma_f32_16x16x32_bf16(
            af[m], bfr[nn], acc[m][nn], 0, 0, 0);
    asm volatile("s_waitcnt lgkmcnt(0)" ::: "memory");  // ds_reads complete
    SB0();
    __builtin_amdgcn_s_barrier();  // reads done before buf overwrite
    SB0();
  }

  // epilogue: wave-private [64][36] f32 LDS tile; two col-halves;
  // residual from xbf (bf16) when use_bf, else fp32 x.
  int rowbase = bm * 128 + wr * 64;
  int clamped = rowbase + lane;
  if (clamped > M - 1) clamped = M - 1;
  float cbl = cb[clamped];
  float* ltile = (float*)smem + w * 2304;  // 64*36 floats/wave
  int prow = lane >> 3;
  int pc4 = lane & 7;
  #pragma unroll
  for (int h = 0; h < 2; ++h) {
    #pragma unroll
    for (int m = 0; m < 4; ++m)
      #pragma unroll
      for (int n2 = 0; n2 < 2; ++n2)
        #pragma unroll
        for (int rr = 0; rr < 4; ++rr) {
          int row = m * 16 + lhi * 4 + rr;
          ltile[row * 36 + n2 * 16 + (lane & 15)] = acc[m][h * 2 + n2][rr];
        }
    int gcol = bn * 128 + wc * 64 + h * 32 + pc4 * 4;
    float4 bb = *(const float4*)(bias + gcol);
    #pragma unroll
    for (int p = 0; p < 8; ++p) {
      int row = p * 8 + prow;
      int gr = rowbase + row;
      float cbr = __shfl(cbl, row);
      if (gr < M) {
        float4 v = *(const float4*)(ltile + row * 36 + pc4 * 4);
        float xr0, xr1, xr2, xr3;
        if (use_bf) {
          bf16x4 xv = *(const bf16x4*)(xb + (size_t)gr * DD + gcol);
          xr0 = (float)xv[0]; xr1 = (float)xv[1];
          xr2 = (float)xv[2]; xr3 = (float)xv[3];
        } else {
          float4 xv = *(const float4*)(x + (size_t)gr * DD + gcol);
          xr0 = xv.x; xr1 = xv.y; xr2 = xv.z; xr3 = xv.w;
        }
        float4 o;
        o.x = xr0 - STEPSZ * (v.x + cbr * bb.x);
        o.y = xr1 - STEPSZ * (v.y + cbr * bb.y);
        o.z = xr2 - STEPSZ * (v.z + cbr * bb.z);
        o.w = xr3 - STEPSZ * (v.w + cbr * bb.w);
        *(float4*)(out + (size_t)gr * DD + gcol) = o;
      }
    }
  }
}

extern "C" void kernel_launch(void* const* d_in, const int* in_sizes, int n_in,
                              void* d_out, int out_size, void* d_ws,
                              size_t ws_size, hipStream_t stream) {
  const float* x = (const float*)d_in[0];
  const float* W = (const float*)d_in[1];
  const float* b = (const float*)d_in[2];
  const float* wsheaf = (const float*)d_in[3];
  const int* ei = (const int*)d_in[4];
  const int* right = (const int*)d_in[5];
  (void)right;
  int N = in_sizes[0] / DD;  // 50000
  int E = in_sizes[5];       // 200000

  char* ws = (char*)d_ws;
  size_t p = 0;
  auto alloc = [&](size_t bytes) -> char* {
    char* r = ws + p;
    p += (bytes + 255) & ~(size_t)255;
    return r;
  };
  bf16* ub = (bf16*)alloc((size_t)N * DD * 2);         // 51.2 MB
  float* cval = (float*)alloc((size_t)N * SLOTS * 4);  // 6.4 MB
  int* ccol = (int*)alloc((size_t)N * SLOTS * 4);      // 6.4 MB
  float* s = (float*)alloc((size_t)N * 4);
  float* t = (float*)alloc((size_t)N * 4);
  float* cb = (float*)alloc((size_t)N * 4);
  bf16* wbf = (bf16*)alloc((size_t)DD * DD * 2);
  char* zblock = alloc((size_t)N * 8);
  float* diag_maps = (float*)zblock;
  int* fill = (int*)(zblock + (size_t)N * 4);

  // xbf: prefer ws (enables bf16 residual read in k_gemm); else lower half
  // of d_out (then only k_gather reads it, before k_gemm writes d_out).
  size_t xbf_bytes = (size_t)N * DD * 2;
  int use_bf = (p + xbf_bytes) <= ws_size;
  bf16* xbf = use_bf ? (bf16*)alloc(xbf_bytes) : (bf16*)d_out;

  k_prep<<<256 + (N + 3) / 4, 256, 0, stream>>>(x, wsheaf, W, xbf, wbf, s, t,
                                                diag_maps, fill, N);
  k_fill<<<(E + 255) / 256, 256, 0, stream>>>(ei, s, t, diag_maps, fill, ccol,
                                              cval, E);
  k_gather<<<(N + 3) / 4, 256, 0, stream>>>(xbf, diag_maps, fill, ccol, cval,
                                            ub, cb, N);
  int MT = (N + 127) / 128;
  int nwg = MT * 4;
  k_gemm<<<nwg, 256, 0, stream>>>(ub, wbf, b, x, xbf, cb, (float*)d_out, N,
                                  nwg, use_bf);
}